// Round 3
// baseline (723.424 us; speedup 1.0000x reference)
//
#include <hip/hip_runtime.h>
#include <math.h>

#define NN 100000
#define NE 1000000
// H = 64 channels, hard-coded throughout.

// ---------------- degree / norm precompute ----------------

__global__ __launch_bounds__(256) void k_init_deg(float* __restrict__ deg) {
  int i = blockIdx.x * 256 + threadIdx.x;
  if (i < NN) deg[i] = 1.0f;  // self-loop weight
}

__global__ __launch_bounds__(256) void k_scatter_deg(const int* __restrict__ dst,
                                                     const float* __restrict__ ew,
                                                     float* __restrict__ deg) {
  int e = blockIdx.x * 256 + threadIdx.x;
  if (e < NE) unsafeAtomicAdd(&deg[dst[e]], ew[e]);
}

__global__ __launch_bounds__(256) void k_dinv(const float* __restrict__ deg,
                                              float* __restrict__ dinv) {
  int i = blockIdx.x * 256 + threadIdx.x;
  if (i < NN) {
    float d = deg[i];
    dinv[i] = (d > 0.0f) ? (1.0f / sqrtf(d)) : 0.0f;
  }
}

__global__ __launch_bounds__(256) void k_norm(const int* __restrict__ src,
                                              const int* __restrict__ dst,
                                              const float* __restrict__ ew,
                                              const float* __restrict__ dinv,
                                              float* __restrict__ nrm) {
  int e = blockIdx.x * 256 + threadIdx.x;
  if (e < NE) nrm[e] = dinv[src[e]] * ew[e] * dinv[dst[e]];
}

// ---------------- 64x64 GEMM: Y[N,64] = X[N,64] @ W[64,64] ----------------
// One wave per node-row. Each lane owns output column `lane`, holding W's
// column in 64 VGPRs. Row elements broadcast via v_readlane.

__global__ __launch_bounds__(256) void k_gemm64(const float* __restrict__ X,
                                                const float* __restrict__ W,
                                                float* __restrict__ Y) {
  int lane = threadIdx.x & 63;
  int wid = blockIdx.x * 4 + (threadIdx.x >> 6);
  int nw = gridDim.x * 4;
  float wcol[64];
#pragma unroll
  for (int k = 0; k < 64; ++k) wcol[k] = W[k * 64 + lane];
  for (int node = wid; node < NN; node += nw) {
    float xv = X[node * 64 + lane];
    float acc = 0.0f;
#pragma unroll
    for (int k = 0; k < 64; ++k) {
      float xb = __int_as_float(__builtin_amdgcn_readlane(__float_as_int(xv), k));
      acc = fmaf(xb, wcol[k], acc);
    }
    Y[node * 64 + lane] = acc;
  }
}

// ---------------- aggregation ----------------

// self-loop contribution: h[i,:] = xw[i,:] * dinv[i]^2
__global__ __launch_bounds__(256) void k_agg_init(const float* __restrict__ xw,
                                                  const float* __restrict__ dinv,
                                                  float* __restrict__ h) {
  int i = blockIdx.x * 256 + threadIdx.x;
  if (i < NN * 64) {
    float di = dinv[i >> 6];
    h[i] = xw[i] * di * di;
  }
}

// edge scatter: h[dst,:] += xw[src,:] * norm[e];  64 lanes = 64 channels/edge
__global__ __launch_bounds__(256) void k_scatter_edges(const int* __restrict__ src,
                                                       const int* __restrict__ dst,
                                                       const float* __restrict__ nrm,
                                                       const float* __restrict__ xw,
                                                       float* __restrict__ h) {
  int lane = threadIdx.x & 63;
  int e = blockIdx.x * 4 + (threadIdx.x >> 6);
  if (e < NE) {
    int s = src[e];
    int d = dst[e];
    float nv = nrm[e];
    float v = xw[s * 64 + lane] * nv;
    unsafeAtomicAdd(&h[d * 64 + lane], v);
  }
}

__global__ __launch_bounds__(256) void k_bias_relu(float* __restrict__ h,
                                                   const float* __restrict__ b) {
  int i = blockIdx.x * 256 + threadIdx.x;
  if (i < NN * 64) {
    float v = h[i] + b[i & 63];
    h[i] = v > 0.0f ? v : 0.0f;
  }
}

// ---------------- heads: logits + rescue ratios ----------------

__global__ __launch_bounds__(256) void k_heads(const float* __restrict__ h,
                                               const float* __restrict__ Wn,
                                               const float* __restrict__ bn,
                                               const float* __restrict__ Wr,
                                               const float* __restrict__ br,
                                               float* __restrict__ logits,
                                               float* __restrict__ rr) {
  int lane = threadIdx.x & 63;
  int node = blockIdx.x * 4 + (threadIdx.x >> 6);
  if (node < NN) {
    float v = h[node * 64 + lane];
    float an = v * Wn[lane];
    float ar = v * Wr[lane];
#pragma unroll
    for (int m = 32; m > 0; m >>= 1) {
      an += __shfl_xor(an, m, 64);
      ar += __shfl_xor(ar, m, 64);
    }
    if (lane == 0) {
      logits[node] = an + bn[0];
      float xr = ar + br[0];
      rr[node] = 0.01f / (1.0f + expf(-xr));
    }
  }
}

// ---------------- softmax over N (5 passes, deterministic trees) ----------------

#define RB 256  // reduction grid

__global__ __launch_bounds__(256) void k_smax_partial(const float* __restrict__ logits,
                                                      float* __restrict__ part) {
  __shared__ float s[256];
  float m = -INFINITY;
  for (int i = blockIdx.x * 256 + threadIdx.x; i < NN; i += RB * 256)
    m = fmaxf(m, logits[i]);
  s[threadIdx.x] = m;
  __syncthreads();
  for (int w = 128; w > 0; w >>= 1) {
    if (threadIdx.x < w) s[threadIdx.x] = fmaxf(s[threadIdx.x], s[threadIdx.x + w]);
    __syncthreads();
  }
  if (threadIdx.x == 0) part[blockIdx.x] = s[0];
}

__global__ __launch_bounds__(256) void k_smax_final(const float* __restrict__ part,
                                                    float* __restrict__ gmax) {
  __shared__ float s[256];
  s[threadIdx.x] = part[threadIdx.x];
  __syncthreads();
  for (int w = 128; w > 0; w >>= 1) {
    if (threadIdx.x < w) s[threadIdx.x] = fmaxf(s[threadIdx.x], s[threadIdx.x + w]);
    __syncthreads();
  }
  if (threadIdx.x == 0) gmax[0] = s[0];
}

__global__ __launch_bounds__(256) void k_sexp(const float* __restrict__ logits,
                                              const float* __restrict__ gmax,
                                              float* __restrict__ sel,
                                              float* __restrict__ part) {
  __shared__ float s[256];
  float m = gmax[0];
  float acc = 0.0f;
  for (int i = blockIdx.x * 256 + threadIdx.x; i < NN; i += RB * 256) {
    float e = expf(logits[i] - m);
    sel[i] = e;
    acc += e;
  }
  s[threadIdx.x] = acc;
  __syncthreads();
  for (int w = 128; w > 0; w >>= 1) {
    if (threadIdx.x < w) s[threadIdx.x] += s[threadIdx.x + w];
    __syncthreads();
  }
  if (threadIdx.x == 0) part[blockIdx.x] = s[0];
}

__global__ __launch_bounds__(256) void k_ssum_final(const float* __restrict__ part,
                                                    float* __restrict__ ginv) {
  __shared__ float s[256];
  s[threadIdx.x] = part[threadIdx.x];
  __syncthreads();
  for (int w = 128; w > 0; w >>= 1) {
    if (threadIdx.x < w) s[threadIdx.x] += s[threadIdx.x + w];
    __syncthreads();
  }
  if (threadIdx.x == 0) ginv[0] = 1.0f / s[0];
}

__global__ __launch_bounds__(256) void k_snorm(float* __restrict__ sel,
                                               const float* __restrict__ ginv) {
  int i = blockIdx.x * 256 + threadIdx.x;
  if (i < NN) sel[i] *= ginv[0];
}

// ---------------- launch ----------------

extern "C" void kernel_launch(void* const* d_in, const int* in_sizes, int n_in,
                              void* d_out, int out_size, void* d_ws, size_t ws_size,
                              hipStream_t stream) {
  const float* x  = (const float*)d_in[0];
  const int*   ei = (const int*)d_in[1];   // [2, E] flattened: src then dst
  const float* ew = (const float*)d_in[2];
  const float* W1 = (const float*)d_in[3];
  const float* b1 = (const float*)d_in[4];
  const float* W2 = (const float*)d_in[5];
  const float* b2 = (const float*)d_in[6];
  const float* Wn = (const float*)d_in[7];
  const float* bn = (const float*)d_in[8];
  const float* Wr = (const float*)d_in[9];
  const float* br = (const float*)d_in[10];
  const int* src = ei;
  const int* dst = ei + NE;

  float* ws = (float*)d_ws;
  float* xw     = ws;                               // N*64
  float* h      = xw + (size_t)NN * 64;             // N*64
  float* deg    = h + (size_t)NN * 64;              // N
  float* dinv   = deg + NN;                         // N
  float* logits = dinv + NN;                        // N
  float* nrm    = logits + NN;                      // E
  float* part1  = nrm + NE;                         // 256
  float* part2  = part1 + 256;                      // 256
  float* gmax   = part2 + 256;                      // 1
  float* ginv   = gmax + 1;                         // 1

  float* sel = (float*)d_out;                       // node_selector [N]
  float* rr  = (float*)d_out + NN;                  // rescue_ratios [N]

  int gN   = (NN + 255) / 256;
  int gE   = (NE + 255) / 256;
  int gNH  = (NN * 64 + 255) / 256;
  int gE4  = (NE + 3) / 4;
  int gN4  = (NN + 3) / 4;

  // degree + normalization coefficients (shared by both layers)
  k_init_deg<<<gN, 256, 0, stream>>>(deg);
  k_scatter_deg<<<gE, 256, 0, stream>>>(dst, ew, deg);
  k_dinv<<<gN, 256, 0, stream>>>(deg, dinv);
  k_norm<<<gE, 256, 0, stream>>>(src, dst, ew, dinv, nrm);

  // layer 1
  k_gemm64<<<1024, 256, 0, stream>>>(x, W1, xw);
  k_agg_init<<<gNH, 256, 0, stream>>>(xw, dinv, h);
  k_scatter_edges<<<gE4, 256, 0, stream>>>(src, dst, nrm, xw, h);
  k_bias_relu<<<gNH, 256, 0, stream>>>(h, b1);

  // layer 2
  k_gemm64<<<1024, 256, 0, stream>>>(h, W2, xw);
  k_agg_init<<<gNH, 256, 0, stream>>>(xw, dinv, h);
  k_scatter_edges<<<gE4, 256, 0, stream>>>(src, dst, nrm, xw, h);
  k_bias_relu<<<gNH, 256, 0, stream>>>(h, b2);

  // heads
  k_heads<<<gN4, 256, 0, stream>>>(h, Wn, bn, Wr, br, logits, rr);

  // softmax over logits -> sel
  k_smax_partial<<<RB, 256, 0, stream>>>(logits, part1);
  k_smax_final<<<1, 256, 0, stream>>>(part1, gmax);
  k_sexp<<<RB, 256, 0, stream>>>(logits, gmax, sel, part2);
  k_ssum_final<<<1, 256, 0, stream>>>(part2, ginv);
  k_snorm<<<gN, 256, 0, stream>>>(sel, ginv);
}

// Round 4
// 454.108 us; speedup vs baseline: 1.5931x; 1.5931x over previous
//
#include <hip/hip_runtime.h>
#include <math.h>

#define NN 100000
#define NE 1000000
#define NPART 391  // ceil(NN/256)
// H = 64 channels, hard-coded throughout.

// ---------------- init: deg=1 (self-loop), cnt=0 ----------------

__global__ __launch_bounds__(256) void k_init(float* __restrict__ deg,
                                              int* __restrict__ cnt) {
  int i = blockIdx.x * 256 + threadIdx.x;
  if (i < NN) { deg[i] = 1.0f; cnt[i] = 0; }
}

// ---------------- histogram: weighted degree + edge count per dst ----------------

__global__ __launch_bounds__(256) void k_hist(const int* __restrict__ dst,
                                              const float* __restrict__ ew,
                                              float* __restrict__ deg,
                                              int* __restrict__ cnt) {
  int e = blockIdx.x * 256 + threadIdx.x;
  if (e < NE) {
    int d = dst[e];
    unsafeAtomicAdd(&deg[d], ew[e]);
    atomicAdd(&cnt[d], 1);
  }
}

__global__ __launch_bounds__(256) void k_dinv(const float* __restrict__ deg,
                                              float* __restrict__ dinv) {
  int i = blockIdx.x * 256 + threadIdx.x;
  if (i < NN) {
    float d = deg[i];
    dinv[i] = (d > 0.0f) ? (1.0f / sqrtf(d)) : 0.0f;
  }
}

// ---------------- hierarchical exclusive scan of cnt -> rowptr, cursor ----------------

__global__ __launch_bounds__(256) void k_scan1(const int* __restrict__ cnt,
                                               int* __restrict__ rowptr,
                                               int* __restrict__ part) {
  __shared__ int s[256];
  int i = blockIdx.x * 256 + threadIdx.x;
  int c = (i < NN) ? cnt[i] : 0;
  s[threadIdx.x] = c;
  __syncthreads();
  // inclusive scan
  for (int off = 1; off < 256; off <<= 1) {
    int v = (threadIdx.x >= off) ? s[threadIdx.x - off] : 0;
    __syncthreads();
    s[threadIdx.x] += v;
    __syncthreads();
  }
  if (i < NN) rowptr[i + 1] = s[threadIdx.x];  // chunk-local inclusive
  if (threadIdx.x == 255) part[blockIdx.x] = s[255];
}

__global__ __launch_bounds__(512) void k_scan2(int* __restrict__ part) {
  __shared__ int s[512];
  int c = (threadIdx.x < NPART) ? part[threadIdx.x] : 0;
  s[threadIdx.x] = c;
  __syncthreads();
  for (int off = 1; off < 512; off <<= 1) {
    int v = (threadIdx.x >= off) ? s[threadIdx.x - off] : 0;
    __syncthreads();
    s[threadIdx.x] += v;
    __syncthreads();
  }
  // write EXCLUSIVE offsets back
  if (threadIdx.x < NPART)
    part[threadIdx.x] = (threadIdx.x == 0) ? 0 : s[threadIdx.x - 1];
}

__global__ __launch_bounds__(256) void k_scan3(const int* __restrict__ cnt,
                                               const int* __restrict__ part,
                                               int* __restrict__ rowptr,
                                               int* __restrict__ cursor) {
  int i = blockIdx.x * 256 + threadIdx.x;
  if (i < NN) {
    int incl = rowptr[i + 1] + part[blockIdx.x];
    rowptr[i + 1] = incl;
    cursor[i] = incl - cnt[i];  // exclusive start
    if (i == 0) rowptr[0] = 0;
  }
}

// ---------------- fill: bucket edges by dst, precompute norm value ----------------

__global__ __launch_bounds__(256) void k_fill(const int* __restrict__ src,
                                              const int* __restrict__ dst,
                                              const float* __restrict__ ew,
                                              const float* __restrict__ dinv,
                                              int* __restrict__ cursor,
                                              int* __restrict__ ssrc,
                                              float* __restrict__ sval) {
  int e = blockIdx.x * 256 + threadIdx.x;
  if (e < NE) {
    int s = src[e];
    int d = dst[e];
    float v = dinv[s] * ew[e] * dinv[d];
    int pos = atomicAdd(&cursor[d], 1);
    ssrc[pos] = s;
    sval[pos] = v;
  }
}

// ---------------- 64x64 GEMM: Y[N,64] = X[N,64] @ W[64,64] ----------------
// One wave per node-row; lane owns output column; row broadcast via readlane.

__global__ __launch_bounds__(256) void k_gemm64(const float* __restrict__ X,
                                                const float* __restrict__ W,
                                                float* __restrict__ Y) {
  int lane = threadIdx.x & 63;
  int wid = blockIdx.x * 4 + (threadIdx.x >> 6);
  int nw = gridDim.x * 4;
  float wcol[64];
#pragma unroll
  for (int k = 0; k < 64; ++k) wcol[k] = W[k * 64 + lane];
  for (int node = wid; node < NN; node += nw) {
    float xv = X[node * 64 + lane];
    float acc = 0.0f;
#pragma unroll
    for (int k = 0; k < 64; ++k) {
      float xb = __int_as_float(__builtin_amdgcn_readlane(__float_as_int(xv), k));
      acc = fmaf(xb, wcol[k], acc);
    }
    Y[node * 64 + lane] = acc;
  }
}

// ---------------- layer-1 aggregation: gather + self-loop + bias + ReLU ----------------
// One wave per node; lane = channel.

__global__ __launch_bounds__(256) void k_gather_l1(const float* __restrict__ xw,
                                                   const float* __restrict__ dinv,
                                                   const int* __restrict__ rowptr,
                                                   const int* __restrict__ ssrc,
                                                   const float* __restrict__ sval,
                                                   const float* __restrict__ b,
                                                   float* __restrict__ h) {
  int lane = threadIdx.x & 63;
  int node = blockIdx.x * 4 + (threadIdx.x >> 6);
  if (node >= NN) return;
  float di = dinv[node];
  float acc = xw[node * 64 + lane] * di * di;  // self-loop
  int beg = rowptr[node], end = rowptr[node + 1];
  int j = beg;
  // 2-wide unroll for a little more MLP
  for (; j + 1 < end; j += 2) {
    int s0 = ssrc[j], s1 = ssrc[j + 1];
    float v0 = sval[j], v1 = sval[j + 1];
    float x0 = xw[s0 * 64 + lane];
    float x1 = xw[s1 * 64 + lane];
    acc = fmaf(x0, v0, acc);
    acc = fmaf(x1, v1, acc);
  }
  if (j < end) acc = fmaf(xw[ssrc[j] * 64 + lane], sval[j], acc);
  float r = acc + b[lane];
  h[node * 64 + lane] = r > 0.0f ? r : 0.0f;
}

// ---------------- layer-2 aggregation fused with both heads ----------------
// Never materializes h2: computes relu(agg+b2), reduces the two 64-dots,
// writes logits[node] and rr[node] only.

__global__ __launch_bounds__(256) void k_gather_l2_heads(const float* __restrict__ xw,
                                                         const float* __restrict__ dinv,
                                                         const int* __restrict__ rowptr,
                                                         const int* __restrict__ ssrc,
                                                         const float* __restrict__ sval,
                                                         const float* __restrict__ b2,
                                                         const float* __restrict__ Wn,
                                                         const float* __restrict__ bn,
                                                         const float* __restrict__ Wr,
                                                         const float* __restrict__ br,
                                                         float* __restrict__ logits,
                                                         float* __restrict__ rr) {
  int lane = threadIdx.x & 63;
  int node = blockIdx.x * 4 + (threadIdx.x >> 6);
  if (node >= NN) return;
  float di = dinv[node];
  float acc = xw[node * 64 + lane] * di * di;
  int beg = rowptr[node], end = rowptr[node + 1];
  int j = beg;
  for (; j + 1 < end; j += 2) {
    int s0 = ssrc[j], s1 = ssrc[j + 1];
    float v0 = sval[j], v1 = sval[j + 1];
    float x0 = xw[s0 * 64 + lane];
    float x1 = xw[s1 * 64 + lane];
    acc = fmaf(x0, v0, acc);
    acc = fmaf(x1, v1, acc);
  }
  if (j < end) acc = fmaf(xw[ssrc[j] * 64 + lane], sval[j], acc);
  float r = acc + b2[lane];
  r = r > 0.0f ? r : 0.0f;
  float an = r * Wn[lane];
  float ar = r * Wr[lane];
#pragma unroll
  for (int m = 32; m > 0; m >>= 1) {
    an += __shfl_xor(an, m, 64);
    ar += __shfl_xor(ar, m, 64);
  }
  if (lane == 0) {
    logits[node] = an + bn[0];
    float xr = ar + br[0];
    rr[node] = 0.01f / (1.0f + expf(-xr));
  }
}

// ---------------- softmax over N (5 passes, deterministic trees) ----------------

#define RB 256  // reduction grid

__global__ __launch_bounds__(256) void k_smax_partial(const float* __restrict__ logits,
                                                      float* __restrict__ part) {
  __shared__ float s[256];
  float m = -INFINITY;
  for (int i = blockIdx.x * 256 + threadIdx.x; i < NN; i += RB * 256)
    m = fmaxf(m, logits[i]);
  s[threadIdx.x] = m;
  __syncthreads();
  for (int w = 128; w > 0; w >>= 1) {
    if (threadIdx.x < w) s[threadIdx.x] = fmaxf(s[threadIdx.x], s[threadIdx.x + w]);
    __syncthreads();
  }
  if (threadIdx.x == 0) part[blockIdx.x] = s[0];
}

__global__ __launch_bounds__(256) void k_smax_final(const float* __restrict__ part,
                                                    float* __restrict__ gmax) {
  __shared__ float s[256];
  s[threadIdx.x] = part[threadIdx.x];
  __syncthreads();
  for (int w = 128; w > 0; w >>= 1) {
    if (threadIdx.x < w) s[threadIdx.x] = fmaxf(s[threadIdx.x], s[threadIdx.x + w]);
    __syncthreads();
  }
  if (threadIdx.x == 0) gmax[0] = s[0];
}

__global__ __launch_bounds__(256) void k_sexp(const float* __restrict__ logits,
                                              const float* __restrict__ gmax,
                                              float* __restrict__ sel,
                                              float* __restrict__ part) {
  __shared__ float s[256];
  float m = gmax[0];
  float acc = 0.0f;
  for (int i = blockIdx.x * 256 + threadIdx.x; i < NN; i += RB * 256) {
    float e = expf(logits[i] - m);
    sel[i] = e;
    acc += e;
  }
  s[threadIdx.x] = acc;
  __syncthreads();
  for (int w = 128; w > 0; w >>= 1) {
    if (threadIdx.x < w) s[threadIdx.x] += s[threadIdx.x + w];
    __syncthreads();
  }
  if (threadIdx.x == 0) part[blockIdx.x] = s[0];
}

__global__ __launch_bounds__(256) void k_ssum_final(const float* __restrict__ part,
                                                    float* __restrict__ ginv) {
  __shared__ float s[256];
  s[threadIdx.x] = part[threadIdx.x];
  __syncthreads();
  for (int w = 128; w > 0; w >>= 1) {
    if (threadIdx.x < w) s[threadIdx.x] += s[threadIdx.x + w];
    __syncthreads();
  }
  if (threadIdx.x == 0) ginv[0] = 1.0f / s[0];
}

__global__ __launch_bounds__(256) void k_snorm(float* __restrict__ sel,
                                               const float* __restrict__ ginv) {
  int i = blockIdx.x * 256 + threadIdx.x;
  if (i < NN) sel[i] *= ginv[0];
}

// ---------------- launch ----------------

extern "C" void kernel_launch(void* const* d_in, const int* in_sizes, int n_in,
                              void* d_out, int out_size, void* d_ws, size_t ws_size,
                              hipStream_t stream) {
  const float* x  = (const float*)d_in[0];
  const int*   ei = (const int*)d_in[1];   // [2, E]: src row then dst row
  const float* ew = (const float*)d_in[2];
  const float* W1 = (const float*)d_in[3];
  const float* b1 = (const float*)d_in[4];
  const float* W2 = (const float*)d_in[5];
  const float* b2 = (const float*)d_in[6];
  const float* Wn = (const float*)d_in[7];
  const float* bn = (const float*)d_in[8];
  const float* Wr = (const float*)d_in[9];
  const float* br = (const float*)d_in[10];
  const int* src = ei;
  const int* dst = ei + NE;

  float* ws = (float*)d_ws;
  float* xw     = ws;                                // N*64
  float* h      = xw + (size_t)NN * 64;              // N*64
  float* deg    = h + (size_t)NN * 64;               // N
  float* dinv   = deg + NN;                          // N
  float* logits = dinv + NN;                         // N
  float* sval   = logits + NN;                       // E
  int*   ssrc   = (int*)(sval + NE);                 // E
  int*   cnt    = ssrc + NE;                         // N
  int*   rowptr = cnt + NN;                          // N+1
  int*   cursor = rowptr + NN + 1;                   // N
  int*   iscan  = cursor + NN;                       // 512 (scan partials)
  float* part1  = (float*)(iscan + 512);             // 256
  float* part2  = part1 + 256;                       // 256
  float* gmax   = part2 + 256;                       // 1
  float* ginv   = gmax + 1;                          // 1

  float* sel = (float*)d_out;                        // node_selector [N]
  float* rr  = (float*)d_out + NN;                   // rescue_ratios [N]

  int gN  = (NN + 255) / 256;        // 391 == NPART
  int gE  = (NE + 255) / 256;
  int gN4 = (NN + 3) / 4;

  // ---- CSR build (once, shared by both layers) ----
  k_init<<<gN, 256, 0, stream>>>(deg, cnt);
  k_hist<<<gE, 256, 0, stream>>>(dst, ew, deg, cnt);
  k_dinv<<<gN, 256, 0, stream>>>(deg, dinv);
  k_scan1<<<gN, 256, 0, stream>>>(cnt, rowptr, iscan);
  k_scan2<<<1, 512, 0, stream>>>(iscan);
  k_scan3<<<gN, 256, 0, stream>>>(cnt, iscan, rowptr, cursor);
  k_fill<<<gE, 256, 0, stream>>>(src, dst, ew, dinv, cursor, ssrc, sval);

  // ---- layer 1: gemm -> gather(+self-loop+bias+relu) ----
  k_gemm64<<<1024, 256, 0, stream>>>(x, W1, xw);
  k_gather_l1<<<gN4, 256, 0, stream>>>(xw, dinv, rowptr, ssrc, sval, b1, h);

  // ---- layer 2: gemm -> gather fused with heads (h2 never materialized) ----
  k_gemm64<<<1024, 256, 0, stream>>>(h, W2, xw);
  k_gather_l2_heads<<<gN4, 256, 0, stream>>>(xw, dinv, rowptr, ssrc, sval,
                                             b2, Wn, bn, Wr, br, logits, rr);

  // ---- softmax over logits -> sel ----
  k_smax_partial<<<RB, 256, 0, stream>>>(logits, part1);
  k_smax_final<<<1, 256, 0, stream>>>(part1, gmax);
  k_sexp<<<RB, 256, 0, stream>>>(logits, gmax, sel, part2);
  k_ssum_final<<<1, 256, 0, stream>>>(part2, ginv);
  k_snorm<<<gN, 256, 0, stream>>>(sel, ginv);
}

// Round 5
// 376.212 us; speedup vs baseline: 1.9229x; 1.2071x over previous
//
#include <hip/hip_runtime.h>
#include <math.h>

#define NN 100000
#define NE 1000000
#define CAP 32      // bucket capacity per node; degrees ~Poisson(10), max ~27
#define OVCAP 4096  // overflow list capacity (correct fallback, ~never used)
// H = 64 channels, hard-coded throughout.

// ---------------- init ----------------

__global__ __launch_bounds__(256) void k_init(int* __restrict__ cnt,
                                              int* __restrict__ ovf_n) {
  int i = blockIdx.x * 256 + threadIdx.x;
  if (i < NN) cnt[i] = 0;
  if (i == 0) ovf_n[0] = 0;
}

// ---------------- bucket edges by dst: one atomic + one 8B store per edge ----------------

__global__ __launch_bounds__(256) void k_bucket(const int* __restrict__ src,
                                                const int* __restrict__ dst,
                                                const float* __restrict__ ew,
                                                int* __restrict__ cnt,
                                                int2* __restrict__ bucket,
                                                int4* __restrict__ ovf,
                                                int* __restrict__ ovf_n) {
  int e = blockIdx.x * 256 + threadIdx.x;
  if (e < NE) {
    int s = src[e];
    int d = dst[e];
    float w = ew[e];
    int pos = atomicAdd(&cnt[d], 1);
    if (pos < CAP) {
      bucket[d * CAP + pos] = make_int2(s, __float_as_int(w));
    } else {
      int t = atomicAdd(ovf_n, 1);
      if (t < OVCAP) ovf[t] = make_int4(s, d, __float_as_int(w), 0);
    }
  }
}

// ---------------- weighted degree (no atomics): sum own bucket + self-loop ----------------

__global__ __launch_bounds__(256) void k_degsum(const int* __restrict__ cnt,
                                                const int2* __restrict__ bucket,
                                                const int4* __restrict__ ovf,
                                                const int* __restrict__ ovf_n,
                                                float* __restrict__ dinv) {
  int i = blockIdx.x * 256 + threadIdx.x;
  if (i >= NN) return;
  int c = cnt[i];
  int cc = c < CAP ? c : CAP;
  float dsum = 1.0f;  // self-loop weight
  const int2* bk = bucket + (size_t)i * CAP;
  for (int j = 0; j < cc; ++j) dsum += __int_as_float(bk[j].y);
  if (c > CAP) {
    int on = ovf_n[0]; if (on > OVCAP) on = OVCAP;
    for (int t = 0; t < on; ++t) {
      int4 o = ovf[t];
      if (o.y == i) dsum += __int_as_float(o.z);
    }
  }
  dinv[i] = 1.0f / sqrtf(dsum);  // dsum >= 1 always
}

// ---------------- 64x64 GEMM: Y[N,64] = X[N,64] @ W[64,64] ----------------
// One wave per node-row; lane owns output column; row broadcast via readlane.

__global__ __launch_bounds__(256) void k_gemm64(const float* __restrict__ X,
                                                const float* __restrict__ W,
                                                float* __restrict__ Y) {
  int lane = threadIdx.x & 63;
  int wid = blockIdx.x * 4 + (threadIdx.x >> 6);
  int nw = gridDim.x * 4;
  float wcol[64];
#pragma unroll
  for (int k = 0; k < 64; ++k) wcol[k] = W[k * 64 + lane];
  for (int node = wid; node < NN; node += nw) {
    float xv = X[node * 64 + lane];
    float acc = 0.0f;
#pragma unroll
    for (int k = 0; k < 64; ++k) {
      float xb = __int_as_float(__builtin_amdgcn_readlane(__float_as_int(xv), k));
      acc = fmaf(xb, wcol[k], acc);
    }
    Y[node * 64 + lane] = acc;
  }
}

// ---------------- layer-1 aggregation: gather + self-loop + bias + ReLU ----------------
// One wave per node; lane = channel. norm computed on the fly.

__global__ __launch_bounds__(256) void k_gather_l1(const float* __restrict__ xw,
                                                   const float* __restrict__ dinv,
                                                   const int* __restrict__ cnt,
                                                   const int2* __restrict__ bucket,
                                                   const int4* __restrict__ ovf,
                                                   const int* __restrict__ ovf_n,
                                                   const float* __restrict__ b,
                                                   float* __restrict__ h) {
  int lane = threadIdx.x & 63;
  int node = blockIdx.x * 4 + (threadIdx.x >> 6);
  if (node >= NN) return;
  float di = dinv[node];
  float acc = xw[node * 64 + lane] * di * di;  // self-loop
  int c = cnt[node];
  int cc = c < CAP ? c : CAP;
  const int2* bk = bucket + (size_t)node * CAP;
  int j = 0;
  for (; j + 1 < cc; j += 2) {
    int2 e0 = bk[j], e1 = bk[j + 1];
    float v0 = dinv[e0.x] * __int_as_float(e0.y) * di;
    float v1 = dinv[e1.x] * __int_as_float(e1.y) * di;
    float x0 = xw[e0.x * 64 + lane];
    float x1 = xw[e1.x * 64 + lane];
    acc = fmaf(x0, v0, acc);
    acc = fmaf(x1, v1, acc);
  }
  if (j < cc) {
    int2 e0 = bk[j];
    acc = fmaf(xw[e0.x * 64 + lane], dinv[e0.x] * __int_as_float(e0.y) * di, acc);
  }
  if (c > CAP) {
    int on = ovf_n[0]; if (on > OVCAP) on = OVCAP;
    for (int t = 0; t < on; ++t) {
      int4 o = ovf[t];
      if (o.y == node)
        acc = fmaf(xw[o.x * 64 + lane], dinv[o.x] * __int_as_float(o.z) * di, acc);
    }
  }
  float r = acc + b[lane];
  h[node * 64 + lane] = r > 0.0f ? r : 0.0f;
}

// ---------------- layer-2 aggregation fused with both heads ----------------

__global__ __launch_bounds__(256) void k_gather_l2_heads(const float* __restrict__ xw,
                                                         const float* __restrict__ dinv,
                                                         const int* __restrict__ cnt,
                                                         const int2* __restrict__ bucket,
                                                         const int4* __restrict__ ovf,
                                                         const int* __restrict__ ovf_n,
                                                         const float* __restrict__ b2,
                                                         const float* __restrict__ Wn,
                                                         const float* __restrict__ bn,
                                                         const float* __restrict__ Wr,
                                                         const float* __restrict__ br,
                                                         float* __restrict__ logits,
                                                         float* __restrict__ rr) {
  int lane = threadIdx.x & 63;
  int node = blockIdx.x * 4 + (threadIdx.x >> 6);
  if (node >= NN) return;
  float di = dinv[node];
  float acc = xw[node * 64 + lane] * di * di;
  int c = cnt[node];
  int cc = c < CAP ? c : CAP;
  const int2* bk = bucket + (size_t)node * CAP;
  int j = 0;
  for (; j + 1 < cc; j += 2) {
    int2 e0 = bk[j], e1 = bk[j + 1];
    float v0 = dinv[e0.x] * __int_as_float(e0.y) * di;
    float v1 = dinv[e1.x] * __int_as_float(e1.y) * di;
    float x0 = xw[e0.x * 64 + lane];
    float x1 = xw[e1.x * 64 + lane];
    acc = fmaf(x0, v0, acc);
    acc = fmaf(x1, v1, acc);
  }
  if (j < cc) {
    int2 e0 = bk[j];
    acc = fmaf(xw[e0.x * 64 + lane], dinv[e0.x] * __int_as_float(e0.y) * di, acc);
  }
  if (c > CAP) {
    int on = ovf_n[0]; if (on > OVCAP) on = OVCAP;
    for (int t = 0; t < on; ++t) {
      int4 o = ovf[t];
      if (o.y == node)
        acc = fmaf(xw[o.x * 64 + lane], dinv[o.x] * __int_as_float(o.z) * di, acc);
    }
  }
  float r = acc + b2[lane];
  r = r > 0.0f ? r : 0.0f;
  float an = r * Wn[lane];
  float ar = r * Wr[lane];
#pragma unroll
  for (int m = 32; m > 0; m >>= 1) {
    an += __shfl_xor(an, m, 64);
    ar += __shfl_xor(ar, m, 64);
  }
  if (lane == 0) {
    logits[node] = an + bn[0];
    float xr = ar + br[0];
    rr[node] = 0.01f / (1.0f + expf(-xr));
  }
}

// ---------------- softmax over N (5 passes, deterministic trees) ----------------

#define RB 256  // reduction grid

__global__ __launch_bounds__(256) void k_smax_partial(const float* __restrict__ logits,
                                                      float* __restrict__ part) {
  __shared__ float s[256];
  float m = -INFINITY;
  for (int i = blockIdx.x * 256 + threadIdx.x; i < NN; i += RB * 256)
    m = fmaxf(m, logits[i]);
  s[threadIdx.x] = m;
  __syncthreads();
  for (int w = 128; w > 0; w >>= 1) {
    if (threadIdx.x < w) s[threadIdx.x] = fmaxf(s[threadIdx.x], s[threadIdx.x + w]);
    __syncthreads();
  }
  if (threadIdx.x == 0) part[blockIdx.x] = s[0];
}

__global__ __launch_bounds__(256) void k_smax_final(const float* __restrict__ part,
                                                    float* __restrict__ gmax) {
  __shared__ float s[256];
  s[threadIdx.x] = part[threadIdx.x];
  __syncthreads();
  for (int w = 128; w > 0; w >>= 1) {
    if (threadIdx.x < w) s[threadIdx.x] = fmaxf(s[threadIdx.x], s[threadIdx.x + w]);
    __syncthreads();
  }
  if (threadIdx.x == 0) gmax[0] = s[0];
}

__global__ __launch_bounds__(256) void k_sexp(const float* __restrict__ logits,
                                              const float* __restrict__ gmax,
                                              float* __restrict__ sel,
                                              float* __restrict__ part) {
  __shared__ float s[256];
  float m = gmax[0];
  float acc = 0.0f;
  for (int i = blockIdx.x * 256 + threadIdx.x; i < NN; i += RB * 256) {
    float e = expf(logits[i] - m);
    sel[i] = e;
    acc += e;
  }
  s[threadIdx.x] = acc;
  __syncthreads();
  for (int w = 128; w > 0; w >>= 1) {
    if (threadIdx.x < w) s[threadIdx.x] += s[threadIdx.x + w];
    __syncthreads();
  }
  if (threadIdx.x == 0) part[blockIdx.x] = s[0];
}

__global__ __launch_bounds__(256) void k_ssum_final(const float* __restrict__ part,
                                                    float* __restrict__ ginv) {
  __shared__ float s[256];
  s[threadIdx.x] = part[threadIdx.x];
  __syncthreads();
  for (int w = 128; w > 0; w >>= 1) {
    if (threadIdx.x < w) s[threadIdx.x] += s[threadIdx.x + w];
    __syncthreads();
  }
  if (threadIdx.x == 0) ginv[0] = 1.0f / s[0];
}

__global__ __launch_bounds__(256) void k_snorm(float* __restrict__ sel,
                                               const float* __restrict__ ginv) {
  int i = blockIdx.x * 256 + threadIdx.x;
  if (i < NN) sel[i] *= ginv[0];
}

// ---------------- launch ----------------

extern "C" void kernel_launch(void* const* d_in, const int* in_sizes, int n_in,
                              void* d_out, int out_size, void* d_ws, size_t ws_size,
                              hipStream_t stream) {
  const float* x  = (const float*)d_in[0];
  const int*   ei = (const int*)d_in[1];   // [2, E]: src row then dst row
  const float* ew = (const float*)d_in[2];
  const float* W1 = (const float*)d_in[3];
  const float* b1 = (const float*)d_in[4];
  const float* W2 = (const float*)d_in[5];
  const float* b2 = (const float*)d_in[6];
  const float* Wn = (const float*)d_in[7];
  const float* bn = (const float*)d_in[8];
  const float* Wr = (const float*)d_in[9];
  const float* br = (const float*)d_in[10];
  const int* src = ei;
  const int* dst = ei + NE;

  // ws layout (word offsets chosen to keep int2/int4 regions 16B-aligned)
  float* ws = (float*)d_ws;
  float* xw     = ws;                                 // 6,400,000 floats
  float* h      = xw + (size_t)NN * 64;               // 6,400,000
  float* dinv   = h + (size_t)NN * 64;                // 100,000
  float* logits = dinv + NN;                          // 100,000
  int2*  bucket = (int2*)(logits + NN);               // NN*CAP int2 = 6,400,000 words
  int*   cnt    = (int*)(bucket + (size_t)NN * CAP);  // 100,000
  int4*  ovf    = (int4*)(cnt + NN);                  // OVCAP int4 (offset 16B-aligned)
  int*   ovf_n  = (int*)(ovf + OVCAP);                // 1
  float* part1  = (float*)(ovf_n + 4);                // 256
  float* part2  = part1 + 256;                        // 256
  float* gmax   = part2 + 256;                        // 1
  float* ginv   = gmax + 1;                           // 1

  float* sel = (float*)d_out;                         // node_selector [N]
  float* rr  = (float*)d_out + NN;                    // rescue_ratios [N]

  int gN  = (NN + 255) / 256;
  int gE  = (NE + 255) / 256;
  int gN4 = (NN + 3) / 4;

  // ---- bucket build (once, shared by both layers) ----
  k_init<<<gN, 256, 0, stream>>>(cnt, ovf_n);
  k_bucket<<<gE, 256, 0, stream>>>(src, dst, ew, cnt, bucket, ovf, ovf_n);
  k_degsum<<<gN, 256, 0, stream>>>(cnt, bucket, ovf, ovf_n, dinv);

  // ---- layer 1: gemm -> gather(+self-loop+bias+relu) ----
  k_gemm64<<<1024, 256, 0, stream>>>(x, W1, xw);
  k_gather_l1<<<gN4, 256, 0, stream>>>(xw, dinv, cnt, bucket, ovf, ovf_n, b1, h);

  // ---- layer 2: gemm -> gather fused with heads (h2 never materialized) ----
  k_gemm64<<<1024, 256, 0, stream>>>(h, W2, xw);
  k_gather_l2_heads<<<gN4, 256, 0, stream>>>(xw, dinv, cnt, bucket, ovf, ovf_n,
                                             b2, Wn, bn, Wr, br, logits, rr);

  // ---- softmax over logits -> sel ----
  k_smax_partial<<<RB, 256, 0, stream>>>(logits, part1);
  k_smax_final<<<1, 256, 0, stream>>>(part1, gmax);
  k_sexp<<<RB, 256, 0, stream>>>(logits, gmax, sel, part2);
  k_ssum_final<<<1, 256, 0, stream>>>(part2, ginv);
  k_snorm<<<gN, 256, 0, stream>>>(sel, ginv);
}

// Round 6
// 336.733 us; speedup vs baseline: 2.1484x; 1.1172x over previous
//
#include <hip/hip_runtime.h>
#include <math.h>

#define NN 100000
#define NE 1000000
#define CAP 32      // bucket capacity per node; degrees ~Poisson(10), max ~27
#define OVCAP 4096  // overflow list capacity (correct fallback, ~never used)
// H = 64 channels, hard-coded throughout.

// ---------------- init ----------------

__global__ __launch_bounds__(256) void k_init(int* __restrict__ cnt,
                                              int* __restrict__ ovf_n) {
  int i = blockIdx.x * 256 + threadIdx.x;
  if (i < NN) cnt[i] = 0;
  if (i == 0) ovf_n[0] = 0;
}

// ---------------- bucket edges by dst: one atomic + one 8B store per edge ----------------

__global__ __launch_bounds__(256) void k_bucket(const int* __restrict__ src,
                                                const int* __restrict__ dst,
                                                const float* __restrict__ ew,
                                                int* __restrict__ cnt,
                                                int2* __restrict__ bucket,
                                                int4* __restrict__ ovf,
                                                int* __restrict__ ovf_n) {
  int e = blockIdx.x * 256 + threadIdx.x;
  if (e < NE) {
    int s = src[e];
    int d = dst[e];
    float w = ew[e];
    int pos = atomicAdd(&cnt[d], 1);
    if (pos < CAP) {
      bucket[d * CAP + pos] = make_int2(s, __float_as_int(w));
    } else {
      int t = atomicAdd(ovf_n, 1);
      if (t < OVCAP) ovf[t] = make_int4(s, d, __float_as_int(w), 0);
    }
  }
}

// ---------------- weighted degree (no atomics): sum own bucket + self-loop ----------------

__global__ __launch_bounds__(256) void k_degsum(const int* __restrict__ cnt,
                                                const int2* __restrict__ bucket,
                                                const int4* __restrict__ ovf,
                                                const int* __restrict__ ovf_n,
                                                float* __restrict__ dinv) {
  int i = blockIdx.x * 256 + threadIdx.x;
  if (i >= NN) return;
  int c = cnt[i];
  int cc = c < CAP ? c : CAP;
  float dsum = 1.0f;  // self-loop weight
  const int2* bk = bucket + (size_t)i * CAP;
  for (int j = 0; j < cc; ++j) dsum += __int_as_float(bk[j].y);
  if (c > CAP) {
    int on = ovf_n[0]; if (on > OVCAP) on = OVCAP;
    for (int t = 0; t < on; ++t) {
      int4 o = ovf[t];
      if (o.y == i) dsum += __int_as_float(o.z);
    }
  }
  dinv[i] = 1.0f / sqrtf(dsum);  // dsum >= 1 always
}

// ---------------- 64x64 GEMM: Y[N,64] = X[N,64] @ W[64,64] ----------------
// One wave per node-row; lane owns output column; row broadcast via readlane.

__global__ __launch_bounds__(256) void k_gemm64(const float* __restrict__ X,
                                                const float* __restrict__ W,
                                                float* __restrict__ Y) {
  int lane = threadIdx.x & 63;
  int wid = blockIdx.x * 4 + (threadIdx.x >> 6);
  int nw = gridDim.x * 4;
  float wcol[64];
#pragma unroll
  for (int k = 0; k < 64; ++k) wcol[k] = W[k * 64 + lane];
  for (int node = wid; node < NN; node += nw) {
    float xv = X[node * 64 + lane];
    float acc = 0.0f;
#pragma unroll
    for (int k = 0; k < 64; ++k) {
      float xb = __int_as_float(__builtin_amdgcn_readlane(__float_as_int(xv), k));
      acc = fmaf(xb, wcol[k], acc);
    }
    Y[node * 64 + lane] = acc;
  }
}

// ---------------- vectorized gather core ----------------
// One wave per node. Lane split: eg = lane>>4 (edge slot 0..3), cq = lane&15
// (channel quad: channels 4cq..4cq+3). Each wave streams 4 edges at a time,
// each lane loading a float4 of the src row -> 4x fewer load instructions and
// 4-8 independent 16B loads in flight. Cross-edge reduction: shfl_xor 16,32.
// Returns float4 acc valid in ALL lanes (channel quad = lane&15).

__device__ __forceinline__ float4 gather_row(const float* __restrict__ xw,
                                             const float* __restrict__ dinv,
                                             const int* __restrict__ cnt,
                                             const int2* __restrict__ bucket,
                                             const int4* __restrict__ ovf,
                                             const int* __restrict__ ovf_n,
                                             int node, int eg, int cq, float di) {
  int c = cnt[node];
  int cc = c < CAP ? c : CAP;
  const int2* bk = bucket + (size_t)node * CAP;
  float4 acc = make_float4(0.f, 0.f, 0.f, 0.f);

  int e0 = 0;
  // unrolled: 8 edges (2 groups) per iteration, unconditional
  for (; e0 + 8 <= cc; e0 += 8) {
    int2 Ea = bk[e0 + eg];
    int2 Eb = bk[e0 + 4 + eg];
    const float4 xa = *(const float4*)(xw + (size_t)Ea.x * 64 + cq * 4);
    const float4 xb = *(const float4*)(xw + (size_t)Eb.x * 64 + cq * 4);
    float va = dinv[Ea.x] * __int_as_float(Ea.y) * di;
    float vb = dinv[Eb.x] * __int_as_float(Eb.y) * di;
    acc.x = fmaf(xa.x, va, acc.x); acc.y = fmaf(xa.y, va, acc.y);
    acc.z = fmaf(xa.z, va, acc.z); acc.w = fmaf(xa.w, va, acc.w);
    acc.x = fmaf(xb.x, vb, acc.x); acc.y = fmaf(xb.y, vb, acc.y);
    acc.z = fmaf(xb.z, vb, acc.z); acc.w = fmaf(xb.w, vb, acc.w);
  }
  // remainder: 4 edges at a time, masked
  for (; e0 < cc; e0 += 4) {
    int e = e0 + eg;
    if (e < cc) {
      int2 E = bk[e];
      const float4 xa = *(const float4*)(xw + (size_t)E.x * 64 + cq * 4);
      float v = dinv[E.x] * __int_as_float(E.y) * di;
      acc.x = fmaf(xa.x, v, acc.x); acc.y = fmaf(xa.y, v, acc.y);
      acc.z = fmaf(xa.z, v, acc.z); acc.w = fmaf(xa.w, v, acc.w);
    }
  }
  // collapse the 4 edge-groups: every lane ends with the total for its cq
  acc.x += __shfl_xor(acc.x, 16, 64); acc.y += __shfl_xor(acc.y, 16, 64);
  acc.z += __shfl_xor(acc.z, 16, 64); acc.w += __shfl_xor(acc.w, 16, 64);
  acc.x += __shfl_xor(acc.x, 32, 64); acc.y += __shfl_xor(acc.y, 32, 64);
  acc.z += __shfl_xor(acc.z, 32, 64); acc.w += __shfl_xor(acc.w, 32, 64);

  // overflow edges (post-reduction: added uniformly on all lanes, once)
  if (c > CAP) {
    int on = ovf_n[0]; if (on > OVCAP) on = OVCAP;
    for (int t = 0; t < on; ++t) {
      int4 o = ovf[t];
      if (o.y == node) {
        const float4 xa = *(const float4*)(xw + (size_t)o.x * 64 + cq * 4);
        float v = dinv[o.x] * __int_as_float(o.z) * di;
        acc.x = fmaf(xa.x, v, acc.x); acc.y = fmaf(xa.y, v, acc.y);
        acc.z = fmaf(xa.z, v, acc.z); acc.w = fmaf(xa.w, v, acc.w);
      }
    }
  }
  // self-loop
  const float4 xs = *(const float4*)(xw + (size_t)node * 64 + cq * 4);
  float dd = di * di;
  acc.x = fmaf(xs.x, dd, acc.x); acc.y = fmaf(xs.y, dd, acc.y);
  acc.z = fmaf(xs.z, dd, acc.z); acc.w = fmaf(xs.w, dd, acc.w);
  return acc;
}

// ---------------- layer-1 aggregation: gather + bias + ReLU ----------------

__global__ __launch_bounds__(256) void k_gather_l1(const float* __restrict__ xw,
                                                   const float* __restrict__ dinv,
                                                   const int* __restrict__ cnt,
                                                   const int2* __restrict__ bucket,
                                                   const int4* __restrict__ ovf,
                                                   const int* __restrict__ ovf_n,
                                                   const float* __restrict__ b,
                                                   float* __restrict__ h) {
  int lane = threadIdx.x & 63;
  int node = blockIdx.x * 4 + (threadIdx.x >> 6);
  if (node >= NN) return;
  int eg = lane >> 4, cq = lane & 15;
  float di = dinv[node];
  float4 acc = gather_row(xw, dinv, cnt, bucket, ovf, ovf_n, node, eg, cq, di);
  const float4 b4 = *(const float4*)(b + cq * 4);
  float4 r;
  r.x = fmaxf(acc.x + b4.x, 0.f); r.y = fmaxf(acc.y + b4.y, 0.f);
  r.z = fmaxf(acc.z + b4.z, 0.f); r.w = fmaxf(acc.w + b4.w, 0.f);
  if (lane < 16) *(float4*)(h + (size_t)node * 64 + cq * 4) = r;
}

// ---------------- layer-2 aggregation fused with both heads ----------------

__global__ __launch_bounds__(256) void k_gather_l2_heads(const float* __restrict__ xw,
                                                         const float* __restrict__ dinv,
                                                         const int* __restrict__ cnt,
                                                         const int2* __restrict__ bucket,
                                                         const int4* __restrict__ ovf,
                                                         const int* __restrict__ ovf_n,
                                                         const float* __restrict__ b2,
                                                         const float* __restrict__ Wn,
                                                         const float* __restrict__ bn,
                                                         const float* __restrict__ Wr,
                                                         const float* __restrict__ br,
                                                         float* __restrict__ logits,
                                                         float* __restrict__ rr) {
  int lane = threadIdx.x & 63;
  int node = blockIdx.x * 4 + (threadIdx.x >> 6);
  if (node >= NN) return;
  int eg = lane >> 4, cq = lane & 15;
  float di = dinv[node];
  float4 acc = gather_row(xw, dinv, cnt, bucket, ovf, ovf_n, node, eg, cq, di);
  const float4 b4 = *(const float4*)(b2 + cq * 4);
  float4 r;
  r.x = fmaxf(acc.x + b4.x, 0.f); r.y = fmaxf(acc.y + b4.y, 0.f);
  r.z = fmaxf(acc.z + b4.z, 0.f); r.w = fmaxf(acc.w + b4.w, 0.f);
  const float4 wn4 = *(const float4*)(Wn + cq * 4);
  const float4 wr4 = *(const float4*)(Wr + cq * 4);
  float an = r.x * wn4.x + r.y * wn4.y + r.z * wn4.z + r.w * wn4.w;
  float ar = r.x * wr4.x + r.y * wr4.y + r.z * wr4.z + r.w * wr4.w;
  // reduce over the 16 channel-quads (each 16-lane group holds identical data)
#pragma unroll
  for (int m = 8; m > 0; m >>= 1) {
    an += __shfl_xor(an, m, 64);
    ar += __shfl_xor(ar, m, 64);
  }
  if (lane == 0) {
    logits[node] = an + bn[0];
    float xr = ar + br[0];
    rr[node] = 0.01f / (1.0f + expf(-xr));
  }
}

// ---------------- softmax over N (5 passes, deterministic trees) ----------------

#define RB 256  // reduction grid

__global__ __launch_bounds__(256) void k_smax_partial(const float* __restrict__ logits,
                                                      float* __restrict__ part) {
  __shared__ float s[256];
  float m = -INFINITY;
  for (int i = blockIdx.x * 256 + threadIdx.x; i < NN; i += RB * 256)
    m = fmaxf(m, logits[i]);
  s[threadIdx.x] = m;
  __syncthreads();
  for (int w = 128; w > 0; w >>= 1) {
    if (threadIdx.x < w) s[threadIdx.x] = fmaxf(s[threadIdx.x], s[threadIdx.x + w]);
    __syncthreads();
  }
  if (threadIdx.x == 0) part[blockIdx.x] = s[0];
}

__global__ __launch_bounds__(256) void k_smax_final(const float* __restrict__ part,
                                                    float* __restrict__ gmax) {
  __shared__ float s[256];
  s[threadIdx.x] = part[threadIdx.x];
  __syncthreads();
  for (int w = 128; w > 0; w >>= 1) {
    if (threadIdx.x < w) s[threadIdx.x] = fmaxf(s[threadIdx.x], s[threadIdx.x + w]);
    __syncthreads();
  }
  if (threadIdx.x == 0) gmax[0] = s[0];
}

__global__ __launch_bounds__(256) void k_sexp(const float* __restrict__ logits,
                                              const float* __restrict__ gmax,
                                              float* __restrict__ sel,
                                              float* __restrict__ part) {
  __shared__ float s[256];
  float m = gmax[0];
  float acc = 0.0f;
  for (int i = blockIdx.x * 256 + threadIdx.x; i < NN; i += RB * 256) {
    float e = expf(logits[i] - m);
    sel[i] = e;
    acc += e;
  }
  s[threadIdx.x] = acc;
  __syncthreads();
  for (int w = 128; w > 0; w >>= 1) {
    if (threadIdx.x < w) s[threadIdx.x] += s[threadIdx.x + w];
    __syncthreads();
  }
  if (threadIdx.x == 0) part[blockIdx.x] = s[0];
}

__global__ __launch_bounds__(256) void k_ssum_final(const float* __restrict__ part,
                                                    float* __restrict__ ginv) {
  __shared__ float s[256];
  s[threadIdx.x] = part[threadIdx.x];
  __syncthreads();
  for (int w = 128; w > 0; w >>= 1) {
    if (threadIdx.x < w) s[threadIdx.x] += s[threadIdx.x + w];
    __syncthreads();
  }
  if (threadIdx.x == 0) ginv[0] = 1.0f / s[0];
}

__global__ __launch_bounds__(256) void k_snorm(float* __restrict__ sel,
                                               const float* __restrict__ ginv) {
  int i = blockIdx.x * 256 + threadIdx.x;
  if (i < NN) sel[i] *= ginv[0];
}

// ---------------- launch ----------------

extern "C" void kernel_launch(void* const* d_in, const int* in_sizes, int n_in,
                              void* d_out, int out_size, void* d_ws, size_t ws_size,
                              hipStream_t stream) {
  const float* x  = (const float*)d_in[0];
  const int*   ei = (const int*)d_in[1];   // [2, E]: src row then dst row
  const float* ew = (const float*)d_in[2];
  const float* W1 = (const float*)d_in[3];
  const float* b1 = (const float*)d_in[4];
  const float* W2 = (const float*)d_in[5];
  const float* b2 = (const float*)d_in[6];
  const float* Wn = (const float*)d_in[7];
  const float* bn = (const float*)d_in[8];
  const float* Wr = (const float*)d_in[9];
  const float* br = (const float*)d_in[10];
  const int* src = ei;
  const int* dst = ei + NE;

  // ws layout (word offsets keep all float4/int2/int4 regions 16B-aligned)
  float* ws = (float*)d_ws;
  float* xw     = ws;                                 // 6,400,000 floats
  float* h      = xw + (size_t)NN * 64;               // 6,400,000
  float* dinv   = h + (size_t)NN * 64;                // 100,000
  float* logits = dinv + NN;                          // 100,000
  int2*  bucket = (int2*)(logits + NN);               // NN*CAP int2 = 6,400,000 words
  int*   cnt    = (int*)(bucket + (size_t)NN * CAP);  // 100,000
  int4*  ovf    = (int4*)(cnt + NN);                  // OVCAP int4
  int*   ovf_n  = (int*)(ovf + OVCAP);                // 1
  float* part1  = (float*)(ovf_n + 4);                // 256
  float* part2  = part1 + 256;                        // 256
  float* gmax   = part2 + 256;                        // 1
  float* ginv   = gmax + 1;                           // 1

  float* sel = (float*)d_out;                         // node_selector [N]
  float* rr  = (float*)d_out + NN;                    // rescue_ratios [N]

  int gN  = (NN + 255) / 256;
  int gE  = (NE + 255) / 256;
  int gN4 = (NN + 3) / 4;

  // ---- bucket build (once, shared by both layers) ----
  k_init<<<gN, 256, 0, stream>>>(cnt, ovf_n);
  k_bucket<<<gE, 256, 0, stream>>>(src, dst, ew, cnt, bucket, ovf, ovf_n);
  k_degsum<<<gN, 256, 0, stream>>>(cnt, bucket, ovf, ovf_n, dinv);

  // ---- layer 1: gemm -> gather(+self-loop+bias+relu) ----
  k_gemm64<<<1024, 256, 0, stream>>>(x, W1, xw);
  k_gather_l1<<<gN4, 256, 0, stream>>>(xw, dinv, cnt, bucket, ovf, ovf_n, b1, h);

  // ---- layer 2: gemm -> gather fused with heads (h2 never materialized) ----
  k_gemm64<<<1024, 256, 0, stream>>>(h, W2, xw);
  k_gather_l2_heads<<<gN4, 256, 0, stream>>>(xw, dinv, cnt, bucket, ovf, ovf_n,
                                             b2, Wn, bn, Wr, br, logits, rr);

  // ---- softmax over logits -> sel ----
  k_smax_partial<<<RB, 256, 0, stream>>>(logits, part1);
  k_smax_final<<<1, 256, 0, stream>>>(part1, gmax);
  k_sexp<<<RB, 256, 0, stream>>>(logits, gmax, sel, part2);
  k_ssum_final<<<1, 256, 0, stream>>>(part2, ginv);
  k_snorm<<<gN, 256, 0, stream>>>(sel, ginv);
}